// Round 12
// baseline (3044.951 us; speedup 1.0000x reference)
//
#include <hip/hip_runtime.h>
#include <cstdint>

#define T_STEPS 1024
#define BATCH   32
#define DIM     1024
#define RANK    128
#define BD      (BATCH*DIM)            // 32768
#define TBD     ((size_t)T_STEPS*BD)   // 33554432

typedef _Float16 half2v __attribute__((ext_vector_type(2)));

__device__ __forceinline__ float dot2f(uint32_t a, uint32_t b, float acc) {
#if __has_builtin(__builtin_amdgcn_fdot2)
  return __builtin_amdgcn_fdot2(__builtin_bit_cast(half2v, a),
                                __builtin_bit_cast(half2v, b), acc, false);
#else
  half2v xx = __builtin_bit_cast(half2v, a);
  half2v yy = __builtin_bit_cast(half2v, b);
  return acc + (float)xx[0]*(float)yy[0] + (float)xx[1]*(float)yy[1];
#endif
}

__device__ __forceinline__ float dot2x4(uint4 w, uint4 h, float acc) {
  acc = dot2f(w.x, h.x, acc); acc = dot2f(w.y, h.y, acc);
  acc = dot2f(w.z, h.z, acc); acc = dot2f(w.w, h.w, acc);
  return acc;
}

__device__ __forceinline__ uint16_t f16b(float x) {
  _Float16 h = (_Float16)x;
  return __builtin_bit_cast(unsigned short, h);
}
__device__ __forceinline__ uint32_t pack2(float a, float b) {
  return (uint32_t)f16b(a) | ((uint32_t)f16b(b) << 16);
}
__device__ __forceinline__ float fast_tanh(float x) {
  float e = __expf(2.0f*x);
  return 1.0f - 2.0f/(e + 1.0f);
}
__device__ __forceinline__ float fast_silu(float zz) {
  return zz / (1.0f + __expf(-zz));
}

// ---- explicit AGPR residency -------------------------------------------------
// At 256 threads / 1 WG/CU (forced via LDS>80KB) the per-lane unified budget is
// 512 regs: 256 arch VGPRs + 256 AGPRs. "=a" asm results are opaque (no remat)
// and live in the AGPR class. R11 failed only because 512-thr configs are
// capped at 128 unified; this config is not.
__device__ __forceinline__ uint32_t a_write(uint32_t v) {
  uint32_t d;
  asm volatile("v_accvgpr_write_b32 %0, %1" : "=a"(d) : "v"(v));
  return d;
}
__device__ __forceinline__ uint32_t a_read(uint32_t av) {
  uint32_t d;
  asm volatile("v_accvgpr_read_b32 %0, %1" : "=v"(d) : "a"(av));
  return d;
}
__device__ __forceinline__ uint4 a_read4(const uint32_t* a4) {
  return make_uint4(a_read(a4[0]), a_read(a4[1]), a_read(a4[2]), a_read(a4[3]));
}

__device__ __forceinline__ void pin4(uint4 &v) {
  asm volatile("" : "+v"(v.x), "+v"(v.y), "+v"(v.z), "+v"(v.w));
}

// quad_perm broadcast of lane K (0..3) within each quad — VALU pipe, no LDS.
template<int K>
__device__ __forceinline__ uint32_t qbcast(uint32_t v) {
  return (uint32_t)__builtin_amdgcn_mov_dpp((int)v, K*0x55, 0xf, 0xf, true);
}
template<int K>
__device__ __forceinline__ uint4 qbcast4(uint4 v) {
  uint4 r;
  r.x = qbcast<K>(v.x); r.y = qbcast<K>(v.y);
  r.z = qbcast<K>(v.z); r.w = qbcast<K>(v.w);
  return r;
}
template<int CTRL>
__device__ __forceinline__ float dpp_xorf(float v) {
  int t = __builtin_amdgcn_mov_dpp(__builtin_bit_cast(int, v), CTRL, 0xf, 0xf, true);
  return __builtin_bit_cast(float, t);
}

// barrier that does NOT drain vmcnt (only LDS ordering needed between phases)
__device__ __forceinline__ void lds_barrier() {
  asm volatile("s_waitcnt lgkmcnt(0)" ::: "memory");
  __builtin_amdgcn_s_barrier();
  __builtin_amdgcn_sched_barrier(0);
}

// ---------------------------------------------------------------------------
// K0: pack weights to f16 pairs in ws (s folded into U), h0 -> h-slot 0.
// ws layout (uint32 words):
//   [0]      vhw  [128][512]  V_h f16 pairs (word = adjacent d-pair)
//   [65536]  uhw2 [1024][64]  U'_h INTERLEAVED column pairs:
//                             word k of row d = pack(U[d][k]*s[k], U[d][k+64]*s[k+64])
//   [131072] vxw  [128][512]
//   [196608] uxw  [1024][64]  (plain pair layout, used by inp_kernel)
// ---------------------------------------------------------------------------
__global__ void prep_kernel(const float* __restrict__ Uh, const float* __restrict__ Vh,
                            const float* __restrict__ sh, const float* __restrict__ Ux,
                            const float* __restrict__ Vx, const float* __restrict__ sx,
                            const float* __restrict__ h0, uint32_t* __restrict__ ws32,
                            float* __restrict__ hout) {
  int i = blockIdx.x*blockDim.x + threadIdx.x;
  int n = gridDim.x*blockDim.x;
  for (int p = i; p < 65536; p += n) {
    int r = p >> 9, dp = p & 511;
    ws32[p] = pack2(Vh[r*1024 + 2*dp], Vh[r*1024 + 2*dp + 1]);
  }
  for (int p = i; p < 65536; p += n) {
    int d = p >> 6, k = p & 63;
    ws32[65536 + p] = pack2(Uh[d*128 + k]      * sh[k],
                            Uh[d*128 + 64 + k] * sh[64 + k]);
  }
  for (int p = i; p < 65536; p += n) {
    int r = p >> 9, dp = p & 511;
    ws32[131072 + p] = pack2(Vx[r*1024 + 2*dp], Vx[r*1024 + 2*dp + 1]);
  }
  for (int p = i; p < 65536; p += n) {
    int d = p >> 6, rp = p & 63;
    ws32[196608 + p] = pack2(Ux[d*128 + 2*rp]   * sx[2*rp],
                             Ux[d*128 + 2*rp+1] * sx[2*rp+1]);
  }
  for (int p = i; p < BD; p += n) hout[p] = h0[p];
}

// ---------------------------------------------------------------------------
// K1: input branch. One WG per timestep t. (unchanged)
// ---------------------------------------------------------------------------
__global__ __launch_bounds__(512, 4) void inp_kernel(
    const float* __restrict__ x, const uint32_t* __restrict__ ws32,
    const float* __restrict__ bias, float* __restrict__ hout) {
  const int t = blockIdx.x;
  const int l = threadIdx.x;  // 0..511
  __shared__ __attribute__((aligned(16))) uint32_t xs[32*516];
  __shared__ __attribute__((aligned(16))) uint16_t svx[BATCH*RANK];

  const float4* xg = (const float4*)(x + (size_t)t*BD);
  #pragma unroll
  for (int k = 0; k < 16; k++) {
    int i = l + 512*k;
    float4 v = xg[i];
    int bb = i >> 8;
    int d4 = i & 255;
    xs[bb*516 + d4*2]     = pack2(v.x, v.y);
    xs[bb*516 + d4*2 + 1] = pack2(v.z, v.w);
  }
  __syncthreads();

  const int q4 = l & 3;
  const int r  = l >> 2;
  const uint4* wrow = (const uint4*)(ws32 + 131072 + r*512);
  float acc0[8], acc1[8];
  #pragma unroll
  for (int bi = 0; bi < 8; bi++) { acc0[bi] = 0.f; acc1[bi] = 0.f; }
  #pragma unroll 4
  for (int J = 0; J < 128; J += 2) {
    uint4 w0 = wrow[J];
    uint4 w1 = wrow[J+1];
    #pragma unroll
    for (int bi = 0; bi < 8; bi++) {
      const uint4* xrow = (const uint4*)(xs + (4*bi + q4)*516);
      uint4 h0v = xrow[J];
      acc0[bi] = dot2f(w0.x, h0v.x, acc0[bi]);
      acc0[bi] = dot2f(w0.y, h0v.y, acc0[bi]);
      acc0[bi] = dot2f(w0.z, h0v.z, acc0[bi]);
      acc0[bi] = dot2f(w0.w, h0v.w, acc0[bi]);
      uint4 h1v = xrow[J+1];
      acc1[bi] = dot2f(w1.x, h1v.x, acc1[bi]);
      acc1[bi] = dot2f(w1.y, h1v.y, acc1[bi]);
      acc1[bi] = dot2f(w1.z, h1v.z, acc1[bi]);
      acc1[bi] = dot2f(w1.w, h1v.w, acc1[bi]);
    }
  }
  #pragma unroll
  for (int bi = 0; bi < 8; bi++)
    svx[(4*bi + q4)*RANK + r] = f16b(acc0[bi] + acc1[bi]);
  __syncthreads();

  const uint4* svx4 = (const uint4*)svx;
  float accb[BATCH];
  #pragma unroll 1
  for (int dd = 0; dd < 2; dd++) {
    int d = l + dd*512;
    const uint4* urow = (const uint4*)(ws32 + 196608 + d*64);
    #pragma unroll
    for (int bi = 0; bi < BATCH; bi++) accb[bi] = 0.f;
    #pragma unroll
    for (int RP = 0; RP < 16; RP++) {
      uint4 w = urow[RP];
      #pragma unroll
      for (int bi = 0; bi < BATCH; bi++) {
        uint4 sv = svx4[bi*16 + RP];
        accb[bi] = dot2f(w.x, sv.x, accb[bi]);
        accb[bi] = dot2f(w.y, sv.y, accb[bi]);
        accb[bi] = dot2f(w.z, sv.z, accb[bi]);
        accb[bi] = dot2f(w.w, sv.w, accb[bi]);
      }
    }
    float bv = bias[d];
    float* cslot = hout + (size_t)(t+1)*BD + d;
    #pragma unroll
    for (int bi = 0; bi < BATCH; bi++)
      cslot[(size_t)bi*DIM] = accb[bi] + bv;
  }
}

// ---------------------------------------------------------------------------
// K2: recurrence v12. One WG (256 thr = 4 waves, 1 wave/SIMD) per batch b.
// The only config that ever grants >128 regs (R1: 256 @ 256thr + LDS>80KB).
// Per-lane unified budget 512: full weight residency, zero L2 streaming:
//   VGPR: V rows 16G+0..9, 16-pair window W -> vw 160 words (pinned);
//         working ~50 -> total ~210 <= 256 (honest fit)
//   AGPR: U rows 4l..4l+3 complete -> 256 words = the whole AGPR file
//   LDS : V rows 16G+10..15 (96 KB, gold interleave) -> forces 1 WG/CU
// Phase A: 16 rows x 16-pair window; 5-level reduce-scatter (dpp xor1/2 +
// shfl xor4/8/16). Phase B: 4 rows/lane; svh quad-read + DPP broadcast;
// U read back from AGPRs (2 cyc/word on VALU — 15x cheaper than L2 remat).
// ---------------------------------------------------------------------------
__global__ __launch_bounds__(256, 1) void rec_kernel(
    const uint32_t* __restrict__ ws32, const float* __restrict__ z,
    float* __restrict__ outb) {
  const int b  = blockIdx.x;
  const int l  = threadIdx.x;  // 0..255
  const int W  = l & 31;       // 16-pair window
  const int G  = l >> 5;       // row-group 0..7 (16 V rows each)
  const int m  = l & 3;
  float* hout = outb + TBD;
  const uint4* vhw4 = (const uint4*)ws32;            // V: row stride 128 uint4
  const uint4* uhw4 = (const uint4*)(ws32 + 65536);  // U: row stride 16 uint4

  __shared__ __attribute__((aligned(16))) uint4    vlds[6144];   // 96 KB
  __shared__ __attribute__((aligned(16))) uint32_t hbuf[640];    // staggered h
  __shared__ __attribute__((aligned(16))) uint32_t svh32[64];    // 256 B

  // V rows 16G+0..9, window [16W,16W+16) pairs -> VGPRs (160 words, pinned)
  uint4 vw[10][4];
  #pragma unroll
  for (int r = 0; r < 10; r++) {
    #pragma unroll
    for (int c = 0; c < 4; c++) vw[r][c] = vhw4[(16*G + r)*128 + W*4 + c];
  }
  #pragma unroll
  for (int r = 0; r < 10; r++) {
    #pragma unroll
    for (int c = 0; c < 4; c++) pin4(vw[r][c]);
  }
  // V rows 16G+10..15 -> vlds, gold interleave: idx = (G*24 + rr*4 + c)*32 + W
  #pragma unroll
  for (int rr = 0; rr < 6; rr++) {
    #pragma unroll
    for (int c = 0; c < 4; c++)
      vlds[(G*24 + rr*4 + c)*32 + W] = vhw4[(16*G + 10 + rr)*128 + W*4 + c];
  }
  // U rows 4l..4l+3 -> AGPRs (256 words = full AGPR file), row by row
  uint32_t ua[4][16][4];
  #pragma unroll
  for (int k = 0; k < 4; k++) {
    #pragma unroll
    for (int J = 0; J < 16; J++) {
      uint4 t0 = uhw4[(4*l + k)*16 + J];
      ua[k][J][0] = a_write(t0.x); ua[k][J][1] = a_write(t0.y);
      ua[k][J][2] = a_write(t0.z); ua[k][J][3] = a_write(t0.w);
    }
  }
  // init hbuf from h0 (pair-word j at 20*(j>>4) + (j&15))
  #pragma unroll
  for (int pp = 0; pp < 2; pp++) {
    int p = l + pp*256;
    const float2 v = ((const float2*)(hout + (size_t)b*DIM))[p];
    hbuf[20*(p>>4) + (p&15)] = pack2(v.x, v.y);
  }
  __syncthreads();

  const float* zp = z + (size_t)b*DIM + 4*l;
  float*       cp = hout + BD + (size_t)b*DIM + 4*l;   // slot t+1: c -> h
  float*       op = outb + (size_t)b*DIM + 4*l;
  const uint4* hb4  = (const uint4*)hbuf;   // window W at uint4 5W + c
  const uint4* svh4 = (const uint4*)svh32;

  #pragma unroll 1
  for (int t = 0; t < T_STEPS; t++) {
    // prefetch c (slot t+1), z (slot t): consumed at end of phase B
    float4 cc = *(const float4*)cp;
    float4 zz = *(const float4*)zp;

    // ---- phase A: 16 rows (10 reg + 6 LDS) x 16-pair window ----
    float a[16];
    #pragma unroll
    for (int i = 0; i < 16; i++) a[i] = 0.f;
    #pragma unroll
    for (int c = 0; c < 4; c++) {
      uint4 hv = hb4[5*W + c];
      a[0] = dot2x4(vw[0][c], hv, a[0]);
      a[1] = dot2x4(vw[1][c], hv, a[1]);
      a[2] = dot2x4(vw[2][c], hv, a[2]);
      a[3] = dot2x4(vw[3][c], hv, a[3]);
      a[4] = dot2x4(vw[4][c], hv, a[4]);
      a[5] = dot2x4(vw[5][c], hv, a[5]);
      a[6] = dot2x4(vw[6][c], hv, a[6]);
      a[7] = dot2x4(vw[7][c], hv, a[7]);
      a[8] = dot2x4(vw[8][c], hv, a[8]);
      a[9] = dot2x4(vw[9][c], hv, a[9]);
      a[10] = dot2x4(vlds[(G*24 + 0*4 + c)*32 + W], hv, a[10]);
      a[11] = dot2x4(vlds[(G*24 + 1*4 + c)*32 + W], hv, a[11]);
      a[12] = dot2x4(vlds[(G*24 + 2*4 + c)*32 + W], hv, a[12]);
      a[13] = dot2x4(vlds[(G*24 + 3*4 + c)*32 + W], hv, a[13]);
      a[14] = dot2x4(vlds[(G*24 + 4*4 + c)*32 + W], hv, a[14]);
      a[15] = dot2x4(vlds[(G*24 + 5*4 + c)*32 + W], hv, a[15]);
    }
    // 5-level reduce-scatter: lane W ends with full sum of row 16G+(W&15)
    float b8[8];
    {
      const bool s0 = (W & 1);
      #pragma unroll
      for (int i = 0; i < 8; i++) {
        float keep = s0 ? a[2*i+1] : a[2*i];
        float send = s0 ? a[2*i]   : a[2*i+1];
        b8[i] = keep + dpp_xorf<0xB1>(send);   // xor1
      }
    }
    float c4[4];
    {
      const bool s1 = (W >> 1) & 1;
      #pragma unroll
      for (int i = 0; i < 4; i++) {
        float keep = s1 ? b8[2*i+1] : b8[2*i];
        float send = s1 ? b8[2*i]   : b8[2*i+1];
        c4[i] = keep + dpp_xorf<0x4E>(send);   // xor2
      }
    }
    float d2[2];
    {
      const bool s2 = (W >> 2) & 1;
      #pragma unroll
      for (int i = 0; i < 2; i++) {
        float keep = s2 ? c4[2*i+1] : c4[2*i];
        float send = s2 ? c4[2*i]   : c4[2*i+1];
        d2[i] = keep + __shfl_xor(send, 4);
      }
    }
    float e1;
    {
      const bool s3 = (W >> 3) & 1;
      float keep = s3 ? d2[1] : d2[0];
      float send = s3 ? d2[0] : d2[1];
      e1 = keep + __shfl_xor(send, 8);
    }
    e1 += __shfl_xor(e1, 16);
    if (W < 16) {
      int row = 16*G + W;                         // 0..127
      int idx = ((row & 63) << 1) | (row >> 6);   // packed (g, g+64) halves
      ((uint16_t*)svh32)[idx] = f16b(e1);
    }
    lds_barrier();

    // ---- phase B: rows d=4l..4l+3; svh quad-read + DPP bcast; U from AGPR --
    float p0 = 0.f, p1 = 0.f, p2 = 0.f, p3 = 0.f;
    #pragma unroll
    for (int q = 0; q < 4; q++) {
      uint4 svm = svh4[4*q + m];
      {
        uint4 sv = qbcast4<0>(svm);
        p0 = dot2x4(a_read4(ua[0][4*q+0]), sv, p0);
        p1 = dot2x4(a_read4(ua[1][4*q+0]), sv, p1);
        p2 = dot2x4(a_read4(ua[2][4*q+0]), sv, p2);
        p3 = dot2x4(a_read4(ua[3][4*q+0]), sv, p3);
      }
      {
        uint4 sv = qbcast4<1>(svm);
        p0 = dot2x4(a_read4(ua[0][4*q+1]), sv, p0);
        p1 = dot2x4(a_read4(ua[1][4*q+1]), sv, p1);
        p2 = dot2x4(a_read4(ua[2][4*q+1]), sv, p2);
        p3 = dot2x4(a_read4(ua[3][4*q+1]), sv, p3);
      }
      {
        uint4 sv = qbcast4<2>(svm);
        p0 = dot2x4(a_read4(ua[0][4*q+2]), sv, p0);
        p1 = dot2x4(a_read4(ua[1][4*q+2]), sv, p1);
        p2 = dot2x4(a_read4(ua[2][4*q+2]), sv, p2);
        p3 = dot2x4(a_read4(ua[3][4*q+2]), sv, p3);
      }
      {
        uint4 sv = qbcast4<3>(svm);
        p0 = dot2x4(a_read4(ua[0][4*q+3]), sv, p0);
        p1 = dot2x4(a_read4(ua[1][4*q+3]), sv, p1);
        p2 = dot2x4(a_read4(ua[2][4*q+3]), sv, p2);
        p3 = dot2x4(a_read4(ua[3][4*q+3]), sv, p3);
      }
    }

    float hv0 = fast_tanh(p0 + cc.x);
    float hv1 = fast_tanh(p1 + cc.y);
    float hv2 = fast_tanh(p2 + cc.z);
    float hv3 = fast_tanh(p3 + cc.w);
    *(float4*)cp = make_float4(hv0, hv1, hv2, hv3);   // h[t+1] (f32 out)
    {
      int j0 = 2*l, j1 = 2*l + 1;
      hbuf[20*(j0>>4) + (j0&15)] = pack2(hv0, hv1);   // h for next step
      hbuf[20*(j1>>4) + (j1&15)] = pack2(hv2, hv3);
    }
    *(float4*)op = make_float4(hv0 * fast_silu(zz.x), hv1 * fast_silu(zz.y),
                               hv2 * fast_silu(zz.z), hv3 * fast_silu(zz.w));
    lds_barrier();

    cp += BD; zp += BD; op += BD;
  }
}

extern "C" void kernel_launch(void* const* d_in, const int* in_sizes, int n_in,
                              void* d_out, int out_size, void* d_ws, size_t ws_size,
                              hipStream_t stream) {
  const float* x  = (const float*)d_in[0];
  const float* z  = (const float*)d_in[1];
  const float* h0 = (const float*)d_in[2];
  const float* Uh = (const float*)d_in[3];
  const float* Vh = (const float*)d_in[4];
  const float* sh = (const float*)d_in[5];
  const float* Ux = (const float*)d_in[6];
  const float* Vx = (const float*)d_in[7];
  const float* sx = (const float*)d_in[8];
  const float* bb = (const float*)d_in[9];
  float* outb = (float*)d_out;
  uint32_t* ws32 = (uint32_t*)d_ws;   // needs 1 MiB

  prep_kernel<<<512, 256, 0, stream>>>(Uh, Vh, sh, Ux, Vx, sx, h0, ws32, outb + TBD);
  inp_kernel<<<T_STEPS, 512, 0, stream>>>(x, ws32, bb, outb + TBD);
  rec_kernel<<<BATCH, 256, 0, stream>>>(ws32, z, outb);
}